// Round 1
// baseline (1479.922 us; speedup 1.0000x reference)
//
#include <hip/hip_runtime.h>
#include <hip/hip_bf16.h>

#define BB  16
#define LL1 2048
#define LL2 2048
#define HH  768

typedef __attribute__((ext_vector_type(4))) float f32x4;
typedef __attribute__((ext_vector_type(8))) short s16x8;

__device__ __forceinline__ unsigned short f2bf_rn(float x) {
  unsigned u = __builtin_bit_cast(unsigned, x);
  u += 0x7FFFu + ((u >> 16) & 1u);
  return (unsigned short)(u >> 16);
}
__device__ __forceinline__ float bf2f(unsigned short h) {
  unsigned u = ((unsigned)h) << 16;
  return __builtin_bit_cast(float, u);
}

// ---------------- K1: g = hi1 @ wg  (bf16x2 3-term MFMA) ----------------
// A: [B*L1][H] row-major, Bw: [H][H] row-major, C: [B*L1][H]
__global__ __launch_bounds__(256) void k_gemm_g(
    const float* __restrict__ A, const float* __restrict__ Bw,
    float* __restrict__ C)
{
  __shared__ unsigned short Ah[128][40], Al[128][40], Bh[128][40], Bl[128][40];
  const int tid  = threadIdx.x;
  const int lane = tid & 63;
  const int wave = tid >> 6;
  const int wm = (wave >> 1) * 64, wn = (wave & 1) * 64;
  const int m0 = blockIdx.y * 128, n0 = blockIdx.x * 128;
  const int fr = lane & 15, kg = (lane >> 4) * 8;
  f32x4 acc[4][4] = {};

  for (int k0 = 0; k0 < HH; k0 += 32) {
    // stage A tile [128 rows][32 k] (k-contiguous in global)
#pragma unroll
    for (int e = 0; e < 4; ++e) {
      int flat = (tid + e * 256) * 4;
      int r = flat >> 5, c = flat & 31;
      f32x4 v = *(const f32x4*)(A + (size_t)(m0 + r) * HH + k0 + c);
#pragma unroll
      for (int q = 0; q < 4; ++q) {
        unsigned short hi = f2bf_rn(v[q]);
        unsigned short lo = f2bf_rn(v[q] - bf2f(hi));
        Ah[r][c + q] = hi; Al[r][c + q] = lo;
      }
    }
    // stage B transposed: Bs[n][k] <- Bw[k0+k][n0+n]
#pragma unroll
    for (int e = 0; e < 4; ++e) {
      int flat = (tid + e * 256) * 4;
      int k = flat >> 7, n = flat & 127;
      f32x4 v = *(const f32x4*)(Bw + (size_t)(k0 + k) * HH + n0 + n);
#pragma unroll
      for (int q = 0; q < 4; ++q) {
        unsigned short hi = f2bf_rn(v[q]);
        unsigned short lo = f2bf_rn(v[q] - bf2f(hi));
        Bh[n + q][k] = hi; Bl[n + q][k] = lo;
      }
    }
    __syncthreads();
    s16x8 ah[4], al[4], bh[4], bl[4];
#pragma unroll
    for (int mi = 0; mi < 4; ++mi) {
      ah[mi] = *(const s16x8*)&Ah[wm + mi * 16 + fr][kg];
      al[mi] = *(const s16x8*)&Al[wm + mi * 16 + fr][kg];
    }
#pragma unroll
    for (int ni = 0; ni < 4; ++ni) {
      bh[ni] = *(const s16x8*)&Bh[wn + ni * 16 + fr][kg];
      bl[ni] = *(const s16x8*)&Bl[wn + ni * 16 + fr][kg];
    }
#pragma unroll
    for (int mi = 0; mi < 4; ++mi)
#pragma unroll
      for (int ni = 0; ni < 4; ++ni) {
        acc[mi][ni] = __builtin_amdgcn_mfma_f32_16x16x32_bf16(ah[mi], bh[ni], acc[mi][ni], 0, 0, 0);
        acc[mi][ni] = __builtin_amdgcn_mfma_f32_16x16x32_bf16(ah[mi], bl[ni], acc[mi][ni], 0, 0, 0);
        acc[mi][ni] = __builtin_amdgcn_mfma_f32_16x16x32_bf16(al[mi], bh[ni], acc[mi][ni], 0, 0, 0);
      }
    __syncthreads();
  }
#pragma unroll
  for (int mi = 0; mi < 4; ++mi)
#pragma unroll
    for (int ni = 0; ni < 4; ++ni)
#pragma unroll
      for (int j = 0; j < 4; ++j) {
        int row = m0 + wm + mi * 16 + (lane >> 4) * 4 + j;
        int col = n0 + wn + ni * 16 + fr;
        C[(size_t)row * HH + col] = acc[mi][ni][j];
      }
}

// ---------------- K2: S = g[b] @ hi2[b]^T  (bf16x2 3-term) ----------------
// A: g[b] [L1][H], B: hi2[b] [L2][H]  (both k-contiguous, B^T GEMM)
__global__ __launch_bounds__(256) void k_scores(
    const float* __restrict__ G, const float* __restrict__ HI2,
    float* __restrict__ S, int b_base)
{
  __shared__ unsigned short Ah[128][40], Al[128][40], Bh[128][40], Bl[128][40];
  const int tid  = threadIdx.x;
  const int lane = tid & 63;
  const int wave = tid >> 6;
  const int wm = (wave >> 1) * 64, wn = (wave & 1) * 64;
  const int z = blockIdx.z, b = b_base + z;
  const int i0 = blockIdx.y * 128, j0 = blockIdx.x * 128;
  const int fr = lane & 15, kg = (lane >> 4) * 8;
  const float* A  = G   + (size_t)b * LL1 * HH;
  const float* Bm = HI2 + (size_t)b * LL2 * HH;
  float* Sp = S + (size_t)z * LL1 * LL2;
  f32x4 acc[4][4] = {};

  for (int k0 = 0; k0 < HH; k0 += 32) {
#pragma unroll
    for (int e = 0; e < 4; ++e) {
      int flat = (tid + e * 256) * 4;
      int r = flat >> 5, c = flat & 31;
      f32x4 va = *(const f32x4*)(A  + (size_t)(i0 + r) * HH + k0 + c);
      f32x4 vb = *(const f32x4*)(Bm + (size_t)(j0 + r) * HH + k0 + c);
#pragma unroll
      for (int q = 0; q < 4; ++q) {
        unsigned short hi = f2bf_rn(va[q]);
        Ah[r][c + q] = hi; Al[r][c + q] = f2bf_rn(va[q] - bf2f(hi));
        hi = f2bf_rn(vb[q]);
        Bh[r][c + q] = hi; Bl[r][c + q] = f2bf_rn(vb[q] - bf2f(hi));
      }
    }
    __syncthreads();
    s16x8 ah[4], al[4], bh[4], bl[4];
#pragma unroll
    for (int mi = 0; mi < 4; ++mi) {
      ah[mi] = *(const s16x8*)&Ah[wm + mi * 16 + fr][kg];
      al[mi] = *(const s16x8*)&Al[wm + mi * 16 + fr][kg];
    }
#pragma unroll
    for (int ni = 0; ni < 4; ++ni) {
      bh[ni] = *(const s16x8*)&Bh[wn + ni * 16 + fr][kg];
      bl[ni] = *(const s16x8*)&Bl[wn + ni * 16 + fr][kg];
    }
#pragma unroll
    for (int mi = 0; mi < 4; ++mi)
#pragma unroll
      for (int ni = 0; ni < 4; ++ni) {
        acc[mi][ni] = __builtin_amdgcn_mfma_f32_16x16x32_bf16(ah[mi], bh[ni], acc[mi][ni], 0, 0, 0);
        acc[mi][ni] = __builtin_amdgcn_mfma_f32_16x16x32_bf16(ah[mi], bl[ni], acc[mi][ni], 0, 0, 0);
        acc[mi][ni] = __builtin_amdgcn_mfma_f32_16x16x32_bf16(al[mi], bh[ni], acc[mi][ni], 0, 0, 0);
      }
    __syncthreads();
  }
#pragma unroll
  for (int mi = 0; mi < 4; ++mi)
#pragma unroll
    for (int ni = 0; ni < 4; ++ni)
#pragma unroll
      for (int j = 0; j < 4; ++j) {
        int row = i0 + wm + mi * 16 + (lane >> 4) * 4 + j;
        int col = j0 + wn + ni * 16 + fr;
        Sp[(size_t)row * LL2 + col] = acc[mi][ni][j];
      }
}

// ---------------- K2b: per-row max + sum(exp) ----------------
__global__ __launch_bounds__(256) void k_rowstats(
    const float* __restrict__ S, float* __restrict__ stats)
{
  const int row = blockIdx.x, z = blockIdx.y;
  const int tid = threadIdx.x, lane = tid & 63, wv = tid >> 6;
  const float* r = S + (size_t)z * LL1 * LL2 + (size_t)row * LL2;
  __shared__ float red[8];
  float x[8];
  float m = -1e30f;
#pragma unroll
  for (int e = 0; e < 8; ++e) { x[e] = r[tid + 256 * e]; m = fmaxf(m, x[e]); }
#pragma unroll
  for (int off = 32; off >= 1; off >>= 1) m = fmaxf(m, __shfl_xor(m, off));
  if (lane == 0) red[wv] = m;
  __syncthreads();
  float mm = fmaxf(fmaxf(red[0], red[1]), fmaxf(red[2], red[3]));
  float l = 0.f;
#pragma unroll
  for (int e = 0; e < 8; ++e) l += __expf(x[e] - mm);
#pragma unroll
  for (int off = 32; off >= 1; off >>= 1) l += __shfl_xor(l, off);
  if (lane == 0) red[4 + wv] = l;
  __syncthreads();
  if (tid == 0) {
    float ls = red[4] + red[5] + red[6] + red[7];
    stats[((size_t)z * LL1 + row) * 2 + 0] = mm;
    stats[((size_t)z * LL1 + row) * 2 + 1] = ls;
  }
}

// ---------------- K3: O = (exp(S - m) @ V) / l ----------------
// P built on-the-fly from S (fp32, L3-resident); V staged transposed bf16.
__global__ __launch_bounds__(512) void k_out(
    const float* __restrict__ S, const float* __restrict__ stats,
    const float* __restrict__ HI2, float* __restrict__ Out, int b_base)
{
  __shared__ unsigned short Vt[256][40];
  const int tid = threadIdx.x, lane = tid & 63, wave = tid >> 6;
  const int z = blockIdx.z, b = b_base + z;
  const int i0 = blockIdx.y * 128, h0 = blockIdx.x * 256;
  const int wm = (wave >> 1) * 32, wn = (wave & 1) * 128;
  const int fr = lane & 15, kg = (lane >> 4) * 8;
  const float* Sp = S + (size_t)z * LL1 * LL2;
  const float* st = stats + (size_t)z * LL1 * 2;
  const float* V  = HI2 + (size_t)b * LL2 * HH;
  f32x4 acc[2][8] = {};
  float mrow[2];
#pragma unroll
  for (int mi = 0; mi < 2; ++mi) mrow[mi] = st[(i0 + wm + mi * 16 + fr) * 2];

  for (int kv = 0; kv < LL2; kv += 32) {
    // stage V transposed: Vt[n][k] <- V[kv+k][h0+n], bf16
#pragma unroll
    for (int e = 0; e < 4; ++e) {
      int flat = (tid + e * 512) * 4;
      int k = flat >> 8, n = flat & 255;
      f32x4 v = *(const f32x4*)(V + (size_t)(kv + k) * HH + h0 + n);
#pragma unroll
      for (int q = 0; q < 4; ++q) Vt[n + q][k] = f2bf_rn(v[q]);
    }
    __syncthreads();
    // A-fragments: P' = exp(S - m), bf16
    s16x8 pa[2];
#pragma unroll
    for (int mi = 0; mi < 2; ++mi) {
      const float* srow = Sp + (size_t)(i0 + wm + mi * 16 + fr) * LL2 + kv + kg;
      f32x4 s0 = *(const f32x4*)srow;
      f32x4 s1 = *(const f32x4*)(srow + 4);
      float mr = mrow[mi];
      s16x8 t;
#pragma unroll
      for (int q = 0; q < 4; ++q) t[q]     = (short)f2bf_rn(__expf(s0[q] - mr));
#pragma unroll
      for (int q = 0; q < 4; ++q) t[4 + q] = (short)f2bf_rn(__expf(s1[q] - mr));
      pa[mi] = t;
    }
#pragma unroll
    for (int ni = 0; ni < 8; ++ni) {
      s16x8 bf = *(const s16x8*)&Vt[wn + ni * 16 + fr][kg];
#pragma unroll
      for (int mi = 0; mi < 2; ++mi)
        acc[mi][ni] = __builtin_amdgcn_mfma_f32_16x16x32_bf16(pa[mi], bf, acc[mi][ni], 0, 0, 0);
    }
    __syncthreads();
  }
#pragma unroll
  for (int mi = 0; mi < 2; ++mi)
#pragma unroll
    for (int j = 0; j < 4; ++j) {
      int row = i0 + wm + mi * 16 + (lane >> 4) * 4 + j;
      float linv = 1.0f / st[row * 2 + 1];
#pragma unroll
      for (int ni = 0; ni < 8; ++ni) {
        int col = h0 + wn + ni * 16 + fr;
        Out[((size_t)b * LL1 + row) * HH + col] = acc[mi][ni][j] * linv;
      }
    }
}

extern "C" void kernel_launch(void* const* d_in, const int* in_sizes, int n_in,
                              void* d_out, int out_size, void* d_ws, size_t ws_size,
                              hipStream_t stream) {
  const float* hi1 = (const float*)d_in[0];
  const float* hi2 = (const float*)d_in[1];
  const float* wg  = (const float*)d_in[2];
  float* out = (float*)d_out;

  char* ws = (char*)d_ws;
  const size_t g_bytes = (size_t)BB * LL1 * HH * 4;         // 100.7 MB
  const size_t s_per_b = (size_t)LL1 * LL2 * 4;             // 16.8 MB
  const size_t st_per_b = (size_t)LL1 * 2 * 4;

  int CB = 1;
  const int cand[5] = {16, 8, 4, 2, 1};
  for (int i = 0; i < 5; ++i) {
    size_t need = g_bytes + (size_t)cand[i] * (s_per_b + st_per_b) + 1024;
    if (need <= ws_size) { CB = cand[i]; break; }
  }

  float* g     = (float*)ws;
  float* Sbuf  = (float*)(ws + g_bytes);
  float* stats = (float*)(ws + g_bytes + (size_t)CB * s_per_b);

  // K1: g = hi1 @ wg over all batches
  k_gemm_g<<<dim3(HH / 128, (BB * LL1) / 128), 256, 0, stream>>>(hi1, wg, g);

  for (int b0 = 0; b0 < BB; b0 += CB) {
    k_scores  <<<dim3(LL2 / 128, LL1 / 128, CB), 256, 0, stream>>>(g, hi2, Sbuf, b0);
    k_rowstats<<<dim3(LL1, CB),                  256, 0, stream>>>(Sbuf, stats);
    k_out     <<<dim3(HH / 256, LL1 / 128, CB),  512, 0, stream>>>(Sbuf, stats, hi2, out, b0);
  }
}

// Round 2
// 962.833 us; speedup vs baseline: 1.5370x; 1.5370x over previous
//
#include <hip/hip_runtime.h>
#include <hip/hip_bf16.h>

#define BB  16
#define LL1 2048
#define LL2 2048
#define HH  768

typedef __attribute__((ext_vector_type(4))) float f32x4;
typedef __attribute__((ext_vector_type(8))) short s16x8;

__device__ __forceinline__ unsigned short f2bf_rn(float x) {
  unsigned u = __builtin_bit_cast(unsigned, x);
  u += 0x7FFFu + ((u >> 16) & 1u);
  return (unsigned short)(u >> 16);
}
__device__ __forceinline__ float bf2f(unsigned short h) {
  unsigned u = ((unsigned)h) << 16;
  return __builtin_bit_cast(float, u);
}

// ---------------- K1: g = hi1 @ wg  (bf16x2 3-term MFMA) ----------------
// A: [B*L1][H] row-major, Bw: [H][H] row-major, C: [B*L1][H]
__global__ __launch_bounds__(256) void k_gemm_g(
    const float* __restrict__ A, const float* __restrict__ Bw,
    float* __restrict__ C)
{
  __shared__ unsigned short Ah[128][40], Al[128][40], Bh[128][40], Bl[128][40];
  const int tid  = threadIdx.x;
  const int lane = tid & 63;
  const int wave = tid >> 6;
  const int wm = (wave >> 1) * 64, wn = (wave & 1) * 64;
  const int m0 = blockIdx.y * 128, n0 = blockIdx.x * 128;
  const int fr = lane & 15, kg = (lane >> 4) * 8;
  f32x4 acc[4][4] = {};

  for (int k0 = 0; k0 < HH; k0 += 32) {
    // stage A tile [128 rows][32 k] (k-contiguous in global)
#pragma unroll
    for (int e = 0; e < 4; ++e) {
      int flat = (tid + e * 256) * 4;
      int r = flat >> 5, c = flat & 31;
      f32x4 v = *(const f32x4*)(A + (size_t)(m0 + r) * HH + k0 + c);
#pragma unroll
      for (int q = 0; q < 4; ++q) {
        unsigned short hi = f2bf_rn(v[q]);
        unsigned short lo = f2bf_rn(v[q] - bf2f(hi));
        Ah[r][c + q] = hi; Al[r][c + q] = lo;
      }
    }
    // stage B transposed: Bs[n][k] <- Bw[k0+k][n0+n]
#pragma unroll
    for (int e = 0; e < 4; ++e) {
      int flat = (tid + e * 256) * 4;
      int k = flat >> 7, n = flat & 127;
      f32x4 v = *(const f32x4*)(Bw + (size_t)(k0 + k) * HH + n0 + n);
#pragma unroll
      for (int q = 0; q < 4; ++q) {
        unsigned short hi = f2bf_rn(v[q]);
        unsigned short lo = f2bf_rn(v[q] - bf2f(hi));
        Bh[n + q][k] = hi; Bl[n + q][k] = lo;
      }
    }
    __syncthreads();
    s16x8 ah[4], al[4], bh[4], bl[4];
#pragma unroll
    for (int mi = 0; mi < 4; ++mi) {
      ah[mi] = *(const s16x8*)&Ah[wm + mi * 16 + fr][kg];
      al[mi] = *(const s16x8*)&Al[wm + mi * 16 + fr][kg];
    }
#pragma unroll
    for (int ni = 0; ni < 4; ++ni) {
      bh[ni] = *(const s16x8*)&Bh[wn + ni * 16 + fr][kg];
      bl[ni] = *(const s16x8*)&Bl[wn + ni * 16 + fr][kg];
    }
#pragma unroll
    for (int mi = 0; mi < 4; ++mi)
#pragma unroll
      for (int ni = 0; ni < 4; ++ni) {
        acc[mi][ni] = __builtin_amdgcn_mfma_f32_16x16x32_bf16(ah[mi], bh[ni], acc[mi][ni], 0, 0, 0);
        acc[mi][ni] = __builtin_amdgcn_mfma_f32_16x16x32_bf16(ah[mi], bl[ni], acc[mi][ni], 0, 0, 0);
        acc[mi][ni] = __builtin_amdgcn_mfma_f32_16x16x32_bf16(al[mi], bh[ni], acc[mi][ni], 0, 0, 0);
      }
    __syncthreads();
  }
#pragma unroll
  for (int mi = 0; mi < 4; ++mi)
#pragma unroll
    for (int ni = 0; ni < 4; ++ni)
#pragma unroll
      for (int j = 0; j < 4; ++j) {
        int row = m0 + wm + mi * 16 + (lane >> 4) * 4 + j;
        int col = n0 + wn + ni * 16 + fr;
        C[(size_t)row * HH + col] = acc[mi][ni][j];
      }
}

// ---------------- K2: S = g[b] @ hi2[b]^T  (bf16x2 3-term) ----------------
__global__ __launch_bounds__(256) void k_scores(
    const float* __restrict__ G, const float* __restrict__ HI2,
    float* __restrict__ S, int b_base)
{
  __shared__ unsigned short Ah[128][40], Al[128][40], Bh[128][40], Bl[128][40];
  const int tid  = threadIdx.x;
  const int lane = tid & 63;
  const int wave = tid >> 6;
  const int wm = (wave >> 1) * 64, wn = (wave & 1) * 64;
  const int z = blockIdx.z, b = b_base + z;
  const int i0 = blockIdx.y * 128, j0 = blockIdx.x * 128;
  const int fr = lane & 15, kg = (lane >> 4) * 8;
  const float* A  = G   + (size_t)b * LL1 * HH;
  const float* Bm = HI2 + (size_t)b * LL2 * HH;
  float* Sp = S + (size_t)z * LL1 * LL2;
  f32x4 acc[4][4] = {};

  for (int k0 = 0; k0 < HH; k0 += 32) {
#pragma unroll
    for (int e = 0; e < 4; ++e) {
      int flat = (tid + e * 256) * 4;
      int r = flat >> 5, c = flat & 31;
      f32x4 va = *(const f32x4*)(A  + (size_t)(i0 + r) * HH + k0 + c);
      f32x4 vb = *(const f32x4*)(Bm + (size_t)(j0 + r) * HH + k0 + c);
#pragma unroll
      for (int q = 0; q < 4; ++q) {
        unsigned short hi = f2bf_rn(va[q]);
        Ah[r][c + q] = hi; Al[r][c + q] = f2bf_rn(va[q] - bf2f(hi));
        hi = f2bf_rn(vb[q]);
        Bh[r][c + q] = hi; Bl[r][c + q] = f2bf_rn(vb[q] - bf2f(hi));
      }
    }
    __syncthreads();
    s16x8 ah[4], al[4], bh[4], bl[4];
#pragma unroll
    for (int mi = 0; mi < 4; ++mi) {
      ah[mi] = *(const s16x8*)&Ah[wm + mi * 16 + fr][kg];
      al[mi] = *(const s16x8*)&Al[wm + mi * 16 + fr][kg];
    }
#pragma unroll
    for (int ni = 0; ni < 4; ++ni) {
      bh[ni] = *(const s16x8*)&Bh[wn + ni * 16 + fr][kg];
      bl[ni] = *(const s16x8*)&Bl[wn + ni * 16 + fr][kg];
    }
#pragma unroll
    for (int mi = 0; mi < 4; ++mi)
#pragma unroll
      for (int ni = 0; ni < 4; ++ni) {
        acc[mi][ni] = __builtin_amdgcn_mfma_f32_16x16x32_bf16(ah[mi], bh[ni], acc[mi][ni], 0, 0, 0);
        acc[mi][ni] = __builtin_amdgcn_mfma_f32_16x16x32_bf16(ah[mi], bl[ni], acc[mi][ni], 0, 0, 0);
        acc[mi][ni] = __builtin_amdgcn_mfma_f32_16x16x32_bf16(al[mi], bh[ni], acc[mi][ni], 0, 0, 0);
      }
    __syncthreads();
  }
#pragma unroll
  for (int mi = 0; mi < 4; ++mi)
#pragma unroll
    for (int ni = 0; ni < 4; ++ni)
#pragma unroll
      for (int j = 0; j < 4; ++j) {
        int row = i0 + wm + mi * 16 + (lane >> 4) * 4 + j;
        int col = j0 + wn + ni * 16 + fr;
        Sp[(size_t)row * LL2 + col] = acc[mi][ni][j];
      }
}

// ---------------- K3: select-and-gather softmax output ----------------
// One wave per row. exp(S-m) underflows except within ~20 of max:
// neglected mass <= 2048*e^-20 ~ 4e-6 -> output error <= ~2e-5 (vs thr 0.1).
// O[row] = sum_{j: S[j] > m-20} exp(S[j]-m) * hi2[j] / l   -- exact fp32.
__global__ __launch_bounds__(256) void k_select(
    const float* __restrict__ S, const float* __restrict__ HI2,
    float* __restrict__ Out, int b_base)
{
  const int tid = threadIdx.x, lane = tid & 63, wv = tid >> 6;
  const int z = blockIdx.y, b = b_base + z;
  const int row = blockIdx.x * 4 + wv;
  const float* srow = S + ((size_t)z * LL1 + row) * LL2;
  const float* V = HI2 + (size_t)b * LL2 * HH;

  // lane owns columns [lane*32, lane*32+32): 8x f32x4 vector loads
  f32x4 sv[8];
#pragma unroll
  for (int e = 0; e < 8; ++e) sv[e] = *(const f32x4*)(srow + lane * 32 + e * 4);

  float m = -1e30f;
#pragma unroll
  for (int e = 0; e < 8; ++e)
#pragma unroll
    for (int q = 0; q < 4; ++q) m = fmaxf(m, sv[e][q]);
#pragma unroll
  for (int off = 32; off >= 1; off >>= 1) m = fmaxf(m, __shfl_xor(m, off));

  const float thr = m - 20.0f;
  float acc[12] = {};
  float lsum = 0.f;

#pragma unroll
  for (int e = 0; e < 8; ++e) {
#pragma unroll
    for (int q = 0; q < 4; ++q) {
      float sval = sv[e][q];
      bool hit = sval > thr;
      unsigned long long mask = __ballot(hit);
      if (!mask) continue;
      float p = hit ? __expf(sval - m) : 0.f;
      lsum += p;
      while (mask) {
        int src = __ffsll((long long)mask) - 1;
        mask &= mask - 1;
        float w = __shfl(p, src);
        int j = src * 32 + e * 4 + q;
        const float* vr = V + (size_t)j * HH;
#pragma unroll
        for (int c = 0; c < 12; ++c) acc[c] = fmaf(w, vr[lane + 64 * c], acc[c]);
      }
    }
  }
#pragma unroll
  for (int off = 32; off >= 1; off >>= 1) lsum += __shfl_xor(lsum, off);
  const float inv = 1.0f / lsum;
  float* orow = Out + ((size_t)b * LL1 + row) * HH;
#pragma unroll
  for (int c = 0; c < 12; ++c) orow[lane + 64 * c] = acc[c] * inv;
}

extern "C" void kernel_launch(void* const* d_in, const int* in_sizes, int n_in,
                              void* d_out, int out_size, void* d_ws, size_t ws_size,
                              hipStream_t stream) {
  const float* hi1 = (const float*)d_in[0];
  const float* hi2 = (const float*)d_in[1];
  const float* wg  = (const float*)d_in[2];
  float* out = (float*)d_out;

  char* ws = (char*)d_ws;
  const size_t g_bytes = (size_t)BB * LL1 * HH * 4;         // 100.7 MB
  const size_t s_per_b = (size_t)LL1 * LL2 * 4;             // 16.8 MB

  int CB = 1;
  const int cand[5] = {16, 8, 4, 2, 1};
  for (int i = 0; i < 5; ++i) {
    size_t need = g_bytes + (size_t)cand[i] * s_per_b + 1024;
    if (need <= ws_size) { CB = cand[i]; break; }
  }

  float* g    = (float*)ws;
  float* Sbuf = (float*)(ws + g_bytes);

  // K1: g = hi1 @ wg over all batches
  k_gemm_g<<<dim3(HH / 128, (BB * LL1) / 128), 256, 0, stream>>>(hi1, wg, g);

  for (int b0 = 0; b0 < BB; b0 += CB) {
    k_scores<<<dim3(LL2 / 128, LL1 / 128, CB), 256, 0, stream>>>(g, hi2, Sbuf, b0);
    k_select<<<dim3(LL1 / 4, CB),              256, 0, stream>>>(Sbuf, hi2, out, b0);
  }
}

// Round 3
// 720.616 us; speedup vs baseline: 2.0537x; 1.3361x over previous
//
#include <hip/hip_runtime.h>
#include <hip/hip_bf16.h>

#define BB  16
#define LL1 2048
#define LL2 2048
#define HH  768

typedef __attribute__((ext_vector_type(4))) float f32x4;
typedef __attribute__((ext_vector_type(8))) short s16x8;
typedef __attribute__((ext_vector_type(4))) unsigned short u16x4;

__device__ __forceinline__ unsigned short f2bf_rn(float x) {
  unsigned u = __builtin_bit_cast(unsigned, x);
  u += 0x7FFFu + ((u >> 16) & 1u);
  return (unsigned short)(u >> 16);
}
__device__ __forceinline__ float bf2f(unsigned short h) {
  unsigned u = ((unsigned)h) << 16;
  return __builtin_bit_cast(float, u);
}

typedef __attribute__((address_space(3))) unsigned int lds_uint;
typedef __attribute__((address_space(1))) const unsigned int glob_uint;
__device__ __forceinline__ void gl_lds16(const void* g, void* l) {
  __builtin_amdgcn_global_load_lds((glob_uint*)g, (lds_uint*)l, 16, 0, 0);
}

// ---------------- split fp32 -> bf16 hi/lo planes ----------------
__global__ __launch_bounds__(256) void k_split(
    const float* __restrict__ in, unsigned short* __restrict__ ph,
    unsigned short* __restrict__ pl, int n4)
{
  int i = blockIdx.x * 256 + threadIdx.x;
  int stride = gridDim.x * 256;
  for (; i < n4; i += stride) {
    f32x4 v = ((const f32x4*)in)[i];
    u16x4 h, l;
#pragma unroll
    for (int q = 0; q < 4; ++q) {
      h[q] = f2bf_rn(v[q]);
      l[q] = f2bf_rn(v[q] - bf2f(h[q]));
    }
    ((u16x4*)ph)[i] = h;
    ((u16x4*)pl)[i] = l;
  }
}

// ---------------- split + transpose wg: Wt[n][k] = wg[k][n] ----------------
__global__ __launch_bounds__(256) void k_split_wt(
    const float* __restrict__ wg, unsigned short* __restrict__ wth,
    unsigned short* __restrict__ wtl)
{
  __shared__ float t[32][33];
  const int k0 = blockIdx.y * 32, n0 = blockIdx.x * 32;
  const int tx = threadIdx.x & 31, ty = threadIdx.x >> 5;  // ty 0..7
#pragma unroll
  for (int r = ty; r < 32; r += 8) t[r][tx] = wg[(size_t)(k0 + r) * HH + n0 + tx];
  __syncthreads();
#pragma unroll
  for (int r = ty; r < 32; r += 8) {
    float v = t[tx][r];  // wg[k0+tx][n0+r]
    unsigned short h = f2bf_rn(v);
    wth[(size_t)(n0 + r) * HH + k0 + tx] = h;
    wtl[(size_t)(n0 + r) * HH + k0 + tx] = f2bf_rn(v - bf2f(h));
  }
}

// ---------------- K1: G = hi1 @ wg, 4-plane bf16 3-term, planes out ----------------
// A planes: [B*L1][H] k-contig; B planes: Wt [N=H][K=H] k-contig.
__global__ __launch_bounds__(256) void k_gemm_p(
    const unsigned short* __restrict__ Ah, const unsigned short* __restrict__ Al,
    const unsigned short* __restrict__ Bh, const unsigned short* __restrict__ Bl,
    unsigned short* __restrict__ Ch, unsigned short* __restrict__ Cl)
{
  __shared__ unsigned short sAh[128 * 32], sAl[128 * 32], sBh[128 * 32], sBl[128 * 32];
  const int tid = threadIdx.x, lane = tid & 63, wave = tid >> 6;
  const int wm = (wave >> 1) * 64, wn = (wave & 1) * 64;
  const int m0 = blockIdx.y * 128, n0 = blockIdx.x * 128;
  const int fr = lane & 15, kg = (lane >> 4) * 8;
  const int rL = lane >> 2, cb = (lane & 3) * 8;
  const unsigned short* pAh = Ah + (size_t)m0 * HH;
  const unsigned short* pAl = Al + (size_t)m0 * HH;
  const unsigned short* pBh = Bh + (size_t)n0 * HH;
  const unsigned short* pBl = Bl + (size_t)n0 * HH;
  f32x4 acc[4][4] = {};

  const int base0 = wave * 1024, base1 = 4096 + wave * 1024; // LDS byte offsets
  const int r0 = wave * 16 + rL, r1 = 64 + wave * 16 + rL;

  for (int k0 = 0; k0 < HH; k0 += 32) {
    gl_lds16(pAh + (size_t)r0 * HH + k0 + cb, (char*)sAh + base0);
    gl_lds16(pAh + (size_t)r1 * HH + k0 + cb, (char*)sAh + base1);
    gl_lds16(pAl + (size_t)r0 * HH + k0 + cb, (char*)sAl + base0);
    gl_lds16(pAl + (size_t)r1 * HH + k0 + cb, (char*)sAl + base1);
    gl_lds16(pBh + (size_t)r0 * HH + k0 + cb, (char*)sBh + base0);
    gl_lds16(pBh + (size_t)r1 * HH + k0 + cb, (char*)sBh + base1);
    gl_lds16(pBl + (size_t)r0 * HH + k0 + cb, (char*)sBl + base0);
    gl_lds16(pBl + (size_t)r1 * HH + k0 + cb, (char*)sBl + base1);
    __syncthreads();
    s16x8 fah[4], fal[4], fbh[4], fbl[4];
#pragma unroll
    for (int mi = 0; mi < 4; ++mi) {
      fah[mi] = *(const s16x8*)&sAh[(wm + mi * 16 + fr) * 32 + kg];
      fal[mi] = *(const s16x8*)&sAl[(wm + mi * 16 + fr) * 32 + kg];
    }
#pragma unroll
    for (int ni = 0; ni < 4; ++ni) {
      fbh[ni] = *(const s16x8*)&sBh[(wn + ni * 16 + fr) * 32 + kg];
      fbl[ni] = *(const s16x8*)&sBl[(wn + ni * 16 + fr) * 32 + kg];
    }
#pragma unroll
    for (int mi = 0; mi < 4; ++mi)
#pragma unroll
      for (int ni = 0; ni < 4; ++ni) {
        acc[mi][ni] = __builtin_amdgcn_mfma_f32_16x16x32_bf16(fah[mi], fbh[ni], acc[mi][ni], 0, 0, 0);
        acc[mi][ni] = __builtin_amdgcn_mfma_f32_16x16x32_bf16(fah[mi], fbl[ni], acc[mi][ni], 0, 0, 0);
        acc[mi][ni] = __builtin_amdgcn_mfma_f32_16x16x32_bf16(fal[mi], fbh[ni], acc[mi][ni], 0, 0, 0);
      }
    __syncthreads();
  }
#pragma unroll
  for (int mi = 0; mi < 4; ++mi)
#pragma unroll
    for (int ni = 0; ni < 4; ++ni)
#pragma unroll
      for (int j = 0; j < 4; ++j) {
        int row = m0 + wm + mi * 16 + (lane >> 4) * 4 + j;
        int col = n0 + wn + ni * 16 + fr;
        float v = acc[mi][ni][j];
        unsigned short h = f2bf_rn(v);
        Ch[(size_t)row * HH + col] = h;
        Cl[(size_t)row * HH + col] = f2bf_rn(v - bf2f(h));
      }
}

// ---------------- K2: S = G[b] @ hi2[b]^T, 4-plane bf16 3-term ----------------
__global__ __launch_bounds__(256) void k_scores_p(
    const unsigned short* __restrict__ Gh, const unsigned short* __restrict__ Gl,
    const unsigned short* __restrict__ H2h, const unsigned short* __restrict__ H2l,
    float* __restrict__ S, int b_base)
{
  __shared__ unsigned short sAh[128 * 32], sAl[128 * 32], sBh[128 * 32], sBl[128 * 32];
  const int tid = threadIdx.x, lane = tid & 63, wave = tid >> 6;
  const int wm = (wave >> 1) * 64, wn = (wave & 1) * 64;
  const int z = blockIdx.z, b = b_base + z;
  const int i0 = blockIdx.y * 128, j0 = blockIdx.x * 128;
  const int fr = lane & 15, kg = (lane >> 4) * 8;
  const int rL = lane >> 2, cb = (lane & 3) * 8;
  const unsigned short* pAh = Gh  + (size_t)b * LL1 * HH + (size_t)i0 * HH;
  const unsigned short* pAl = Gl  + (size_t)b * LL1 * HH + (size_t)i0 * HH;
  const unsigned short* pBh = H2h + (size_t)b * LL2 * HH + (size_t)j0 * HH;
  const unsigned short* pBl = H2l + (size_t)b * LL2 * HH + (size_t)j0 * HH;
  float* Sp = S + (size_t)z * LL1 * LL2;
  f32x4 acc[4][4] = {};

  const int base0 = wave * 1024, base1 = 4096 + wave * 1024;
  const int r0 = wave * 16 + rL, r1 = 64 + wave * 16 + rL;

  for (int k0 = 0; k0 < HH; k0 += 32) {
    gl_lds16(pAh + (size_t)r0 * HH + k0 + cb, (char*)sAh + base0);
    gl_lds16(pAh + (size_t)r1 * HH + k0 + cb, (char*)sAh + base1);
    gl_lds16(pAl + (size_t)r0 * HH + k0 + cb, (char*)sAl + base0);
    gl_lds16(pAl + (size_t)r1 * HH + k0 + cb, (char*)sAl + base1);
    gl_lds16(pBh + (size_t)r0 * HH + k0 + cb, (char*)sBh + base0);
    gl_lds16(pBh + (size_t)r1 * HH + k0 + cb, (char*)sBh + base1);
    gl_lds16(pBl + (size_t)r0 * HH + k0 + cb, (char*)sBl + base0);
    gl_lds16(pBl + (size_t)r1 * HH + k0 + cb, (char*)sBl + base1);
    __syncthreads();
    s16x8 fah[4], fal[4], fbh[4], fbl[4];
#pragma unroll
    for (int mi = 0; mi < 4; ++mi) {
      fah[mi] = *(const s16x8*)&sAh[(wm + mi * 16 + fr) * 32 + kg];
      fal[mi] = *(const s16x8*)&sAl[(wm + mi * 16 + fr) * 32 + kg];
    }
#pragma unroll
    for (int ni = 0; ni < 4; ++ni) {
      fbh[ni] = *(const s16x8*)&sBh[(wn + ni * 16 + fr) * 32 + kg];
      fbl[ni] = *(const s16x8*)&sBl[(wn + ni * 16 + fr) * 32 + kg];
    }
#pragma unroll
    for (int mi = 0; mi < 4; ++mi)
#pragma unroll
      for (int ni = 0; ni < 4; ++ni) {
        acc[mi][ni] = __builtin_amdgcn_mfma_f32_16x16x32_bf16(fah[mi], fbh[ni], acc[mi][ni], 0, 0, 0);
        acc[mi][ni] = __builtin_amdgcn_mfma_f32_16x16x32_bf16(fah[mi], fbl[ni], acc[mi][ni], 0, 0, 0);
        acc[mi][ni] = __builtin_amdgcn_mfma_f32_16x16x32_bf16(fal[mi], fbh[ni], acc[mi][ni], 0, 0, 0);
      }
    __syncthreads();
  }
#pragma unroll
  for (int mi = 0; mi < 4; ++mi)
#pragma unroll
    for (int ni = 0; ni < 4; ++ni)
#pragma unroll
      for (int j = 0; j < 4; ++j) {
        int row = i0 + wm + mi * 16 + (lane >> 4) * 4 + j;
        int col = j0 + wn + ni * 16 + fr;
        Sp[(size_t)row * LL2 + col] = acc[mi][ni][j];
      }
}

// ---------------- K3: select-and-gather softmax output ----------------
__global__ __launch_bounds__(256) void k_select(
    const float* __restrict__ S, const float* __restrict__ HI2,
    float* __restrict__ Out, int b_base)
{
  const int tid = threadIdx.x, lane = tid & 63, wv = tid >> 6;
  const int z = blockIdx.y, b = b_base + z;
  const int row = blockIdx.x * 4 + wv;
  const float* srow = S + ((size_t)z * LL1 + row) * LL2;
  const float* V = HI2 + (size_t)b * LL2 * HH;

  f32x4 sv[8];
#pragma unroll
  for (int e = 0; e < 8; ++e) sv[e] = *(const f32x4*)(srow + lane * 32 + e * 4);

  float m = -1e30f;
#pragma unroll
  for (int e = 0; e < 8; ++e)
#pragma unroll
    for (int q = 0; q < 4; ++q) m = fmaxf(m, sv[e][q]);
#pragma unroll
  for (int off = 32; off >= 1; off >>= 1) m = fmaxf(m, __shfl_xor(m, off));

  const float thr = m - 20.0f;
  float acc[12] = {};
  float lsum = 0.f;

#pragma unroll
  for (int e = 0; e < 8; ++e) {
#pragma unroll
    for (int q = 0; q < 4; ++q) {
      float sval = sv[e][q];
      bool hit = sval > thr;
      unsigned long long mask = __ballot(hit);
      if (!mask) continue;
      float p = hit ? __expf(sval - m) : 0.f;
      lsum += p;
      while (mask) {
        int src = __ffsll((long long)mask) - 1;
        mask &= mask - 1;
        float w = __shfl(p, src);
        int j = src * 32 + e * 4 + q;
        const float* vr = V + (size_t)j * HH;
#pragma unroll
        for (int c = 0; c < 12; ++c) acc[c] = fmaf(w, vr[lane + 64 * c], acc[c]);
      }
    }
  }
#pragma unroll
  for (int off = 32; off >= 1; off >>= 1) lsum += __shfl_xor(lsum, off);
  const float inv = 1.0f / lsum;
  float* orow = Out + ((size_t)b * LL1 + row) * HH;
#pragma unroll
  for (int c = 0; c < 12; ++c) orow[lane + 64 * c] = acc[c] * inv;
}

extern "C" void kernel_launch(void* const* d_in, const int* in_sizes, int n_in,
                              void* d_out, int out_size, void* d_ws, size_t ws_size,
                              hipStream_t stream) {
  const float* hi1 = (const float*)d_in[0];
  const float* hi2 = (const float*)d_in[1];
  const float* wg  = (const float*)d_in[2];
  float* out = (float*)d_out;

  char* ws = (char*)d_ws;
  const size_t plane_elems = (size_t)BB * LL1 * HH;   // 25.17M
  const size_t plane_b = plane_elems * 2;             // 50.33MB
  const size_t wt_b = (size_t)HH * HH * 2;            // 1.18MB
  const size_t s_per_b = (size_t)LL1 * LL2 * 4;       // 16.78MB

  unsigned short* H2h = (unsigned short*)ws;
  unsigned short* H2l = (unsigned short*)(ws + plane_b);
  unsigned short* Gh  = (unsigned short*)(ws + 2 * plane_b);
  unsigned short* Gl  = (unsigned short*)(ws + 3 * plane_b);
  unsigned short* Wth = (unsigned short*)(ws + 4 * plane_b);
  unsigned short* Wtl = (unsigned short*)(ws + 4 * plane_b + wt_b);
  char* X = ws + 4 * plane_b + 2 * wt_b;              // aliased region
  unsigned short* H1h = (unsigned short*)X;
  unsigned short* H1l = (unsigned short*)(X + plane_b);
  float* Sbuf = (float*)X;

  const size_t fixed = 4 * plane_b + 2 * wt_b;
  int CB = 1;
  const int cand[5] = {16, 8, 4, 2, 1};
  for (int i = 0; i < 5; ++i) {
    size_t xneed = (size_t)cand[i] * s_per_b;
    if (xneed < 2 * plane_b) xneed = 2 * plane_b;     // X also holds H1 planes
    if (fixed + xneed + 1024 <= ws_size) { CB = cand[i]; break; }
  }

  k_split<<<4096, 256, 0, stream>>>(hi1, H1h, H1l, (int)(plane_elems / 4));
  k_split<<<4096, 256, 0, stream>>>(hi2, H2h, H2l, (int)(plane_elems / 4));
  k_split_wt<<<dim3(HH / 32, HH / 32), 256, 0, stream>>>(wg, Wth, Wtl);

  k_gemm_p<<<dim3(HH / 128, (BB * LL1) / 128), 256, 0, stream>>>(H1h, H1l, Wth, Wtl, Gh, Gl);

  for (int b0 = 0; b0 < BB; b0 += CB) {
    k_scores_p<<<dim3(LL2 / 128, LL1 / 128, CB), 256, 0, stream>>>(Gh, Gl, H2h, H2l, Sbuf, b0);
    k_select<<<dim3(LL1 / 4, CB), 256, 0, stream>>>(Sbuf, hi2, out, b0);
  }
}

// Round 5
// 477.573 us; speedup vs baseline: 3.0988x; 1.5089x over previous
//
#include <hip/hip_runtime.h>
#include <hip/hip_bf16.h>

#define BB  16
#define LL1 2048
#define LL2 2048
#define HH  768

typedef __attribute__((ext_vector_type(4))) float f32x4;
typedef __attribute__((ext_vector_type(8))) _Float16 f16x8;
typedef __attribute__((ext_vector_type(4))) _Float16 f16x4;

typedef __attribute__((address_space(3))) unsigned int lds_uint;
typedef __attribute__((address_space(1))) const unsigned int glob_uint;
__device__ __forceinline__ void gl_lds16(const void* g, void* l) {
  __builtin_amdgcn_global_load_lds((glob_uint*)g, (lds_uint*)l, 16, 0, 0);
}

// ---------------- fp32 -> fp16 plane ----------------
__global__ __launch_bounds__(256) void k_split16(
    const float* __restrict__ in, _Float16* __restrict__ p, int n4)
{
  int i = blockIdx.x * 256 + threadIdx.x;
  int stride = gridDim.x * 256;
  for (; i < n4; i += stride) {
    f32x4 v = ((const f32x4*)in)[i];
    f16x4 o;
#pragma unroll
    for (int q = 0; q < 4; ++q) o[q] = (_Float16)v[q];
    ((f16x4*)p)[i] = o;
  }
}

// ---------------- transpose wg -> fp16: Wt[n][k] = wg[k][n] ----------------
__global__ __launch_bounds__(256) void k_split_wt16(
    const float* __restrict__ wg, _Float16* __restrict__ wt)
{
  __shared__ float t[32][33];
  const int k0 = blockIdx.y * 32, n0 = blockIdx.x * 32;
  const int tx = threadIdx.x & 31, ty = threadIdx.x >> 5;  // ty 0..7
#pragma unroll
  for (int r = ty; r < 32; r += 8) t[r][tx] = wg[(size_t)(k0 + r) * HH + n0 + tx];
  __syncthreads();
#pragma unroll
  for (int r = ty; r < 32; r += 8)
    wt[(size_t)(n0 + r) * HH + k0 + tx] = (_Float16)t[tx][r];
}

// ---------------- K1: G = hi1 @ wg, fp16 MFMA, fp16 G out ----------------
__global__ __launch_bounds__(256) void k_gemm_f16(
    const _Float16* __restrict__ A, const _Float16* __restrict__ Bt,
    _Float16* __restrict__ C)
{
  __shared__ _Float16 sA[128 * 32], sB[128 * 32];
  const int tid = threadIdx.x, lane = tid & 63, wave = tid >> 6;
  const int wm = (wave >> 1) * 64, wn = (wave & 1) * 64;
  const int m0 = blockIdx.y * 128, n0 = blockIdx.x * 128;
  const int fr = lane & 15, kg = (lane >> 4) * 8;
  const int rL = lane >> 2, cb = (lane & 3) * 8;
  const _Float16* pA = A  + (size_t)m0 * HH;
  const _Float16* pB = Bt + (size_t)n0 * HH;
  f32x4 acc[4][4] = {};

  const int base0 = wave * 1024, base1 = 4096 + wave * 1024;
  const int r0 = wave * 16 + rL, r1 = 64 + wave * 16 + rL;

  for (int k0 = 0; k0 < HH; k0 += 32) {
    gl_lds16(pA + (size_t)r0 * HH + k0 + cb, (char*)sA + base0);
    gl_lds16(pA + (size_t)r1 * HH + k0 + cb, (char*)sA + base1);
    gl_lds16(pB + (size_t)r0 * HH + k0 + cb, (char*)sB + base0);
    gl_lds16(pB + (size_t)r1 * HH + k0 + cb, (char*)sB + base1);
    __syncthreads();
    f16x8 fa[4], fb[4];
#pragma unroll
    for (int mi = 0; mi < 4; ++mi) fa[mi] = *(const f16x8*)&sA[(wm + mi * 16 + fr) * 32 + kg];
#pragma unroll
    for (int ni = 0; ni < 4; ++ni) fb[ni] = *(const f16x8*)&sB[(wn + ni * 16 + fr) * 32 + kg];
#pragma unroll
    for (int mi = 0; mi < 4; ++mi)
#pragma unroll
      for (int ni = 0; ni < 4; ++ni)
        acc[mi][ni] = __builtin_amdgcn_mfma_f32_16x16x32_f16(fa[mi], fb[ni], acc[mi][ni], 0, 0, 0);
    __syncthreads();
  }
#pragma unroll
  for (int mi = 0; mi < 4; ++mi)
#pragma unroll
    for (int ni = 0; ni < 4; ++ni)
#pragma unroll
      for (int j = 0; j < 4; ++j) {
        int row = m0 + wm + mi * 16 + (lane >> 4) * 4 + j;
        int col = n0 + wn + ni * 16 + fr;
        C[(size_t)row * HH + col] = (_Float16)acc[mi][ni][j];
      }
}

// ---------------- K2: S = G[b] @ hi2[b]^T, fp16 MFMA, S out FP32 ----------------
// (fp16 S-storage was the R4 failure: ulp(130)=0.0625 dominates softmax error.)
__global__ __launch_bounds__(256) void k_scores_f16(
    const _Float16* __restrict__ G, const _Float16* __restrict__ H2,
    float* __restrict__ S, int b_base)
{
  __shared__ _Float16 sA[128 * 32], sB[128 * 32];
  const int tid = threadIdx.x, lane = tid & 63, wave = tid >> 6;
  const int wm = (wave >> 1) * 64, wn = (wave & 1) * 64;
  const int z = blockIdx.z, b = b_base + z;
  const int i0 = blockIdx.y * 128, j0 = blockIdx.x * 128;
  const int fr = lane & 15, kg = (lane >> 4) * 8;
  const int rL = lane >> 2, cb = (lane & 3) * 8;
  const _Float16* pA = G  + (size_t)b * LL1 * HH + (size_t)i0 * HH;
  const _Float16* pB = H2 + (size_t)b * LL2 * HH + (size_t)j0 * HH;
  float* Sp = S + (size_t)z * LL1 * LL2;
  f32x4 acc[4][4] = {};

  const int base0 = wave * 1024, base1 = 4096 + wave * 1024;
  const int r0 = wave * 16 + rL, r1 = 64 + wave * 16 + rL;

  for (int k0 = 0; k0 < HH; k0 += 32) {
    gl_lds16(pA + (size_t)r0 * HH + k0 + cb, (char*)sA + base0);
    gl_lds16(pA + (size_t)r1 * HH + k0 + cb, (char*)sA + base1);
    gl_lds16(pB + (size_t)r0 * HH + k0 + cb, (char*)sB + base0);
    gl_lds16(pB + (size_t)r1 * HH + k0 + cb, (char*)sB + base1);
    __syncthreads();
    f16x8 fa[4], fb[4];
#pragma unroll
    for (int mi = 0; mi < 4; ++mi) fa[mi] = *(const f16x8*)&sA[(wm + mi * 16 + fr) * 32 + kg];
#pragma unroll
    for (int ni = 0; ni < 4; ++ni) fb[ni] = *(const f16x8*)&sB[(wn + ni * 16 + fr) * 32 + kg];
#pragma unroll
    for (int mi = 0; mi < 4; ++mi)
#pragma unroll
      for (int ni = 0; ni < 4; ++ni)
        acc[mi][ni] = __builtin_amdgcn_mfma_f32_16x16x32_f16(fa[mi], fb[ni], acc[mi][ni], 0, 0, 0);
    __syncthreads();
  }
#pragma unroll
  for (int mi = 0; mi < 4; ++mi)
#pragma unroll
    for (int ni = 0; ni < 4; ++ni)
#pragma unroll
      for (int j = 0; j < 4; ++j) {
        int row = i0 + wm + mi * 16 + (lane >> 4) * 4 + j;
        int col = j0 + wn + ni * 16 + fr;
        Sp[(size_t)row * LL2 + col] = acc[mi][ni][j];
      }
}

// ---------------- K3: select-and-gather softmax output (fp32 S) ----------------
__global__ __launch_bounds__(256) void k_select(
    const float* __restrict__ S, const float* __restrict__ HI2,
    float* __restrict__ Out, int b_base)
{
  const int tid = threadIdx.x, lane = tid & 63, wv = tid >> 6;
  const int z = blockIdx.y, b = b_base + z;
  const int row = blockIdx.x * 4 + wv;
  const float* srow = S + ((size_t)z * LL1 + row) * LL2;
  const float* V = HI2 + (size_t)b * LL2 * HH;

  f32x4 sv[8];
#pragma unroll
  for (int e = 0; e < 8; ++e) sv[e] = *(const f32x4*)(srow + lane * 32 + e * 4);

  float m = -1e30f;
#pragma unroll
  for (int e = 0; e < 8; ++e)
#pragma unroll
    for (int q = 0; q < 4; ++q) m = fmaxf(m, sv[e][q]);
#pragma unroll
  for (int off = 32; off >= 1; off >>= 1) m = fmaxf(m, __shfl_xor(m, off));

  const float thr = m - 20.0f;
  float acc[12] = {};
  float lsum = 0.f;

#pragma unroll
  for (int e = 0; e < 8; ++e) {
#pragma unroll
    for (int q = 0; q < 4; ++q) {
      float sval = sv[e][q];
      bool hit = sval > thr;
      unsigned long long mask = __ballot(hit);
      if (!mask) continue;
      float p = hit ? __expf(sval - m) : 0.f;
      lsum += p;
      while (mask) {
        int src = __ffsll((long long)mask) - 1;
        mask &= mask - 1;
        float w = __shfl(p, src);
        int j = src * 32 + e * 4 + q;
        const float* vr = V + (size_t)j * HH;
#pragma unroll
        for (int c = 0; c < 12; ++c) acc[c] = fmaf(w, vr[lane + 64 * c], acc[c]);
      }
    }
  }
#pragma unroll
  for (int off = 32; off >= 1; off >>= 1) lsum += __shfl_xor(lsum, off);
  const float inv = 1.0f / lsum;
  float* orow = Out + ((size_t)b * LL1 + row) * HH;
#pragma unroll
  for (int c = 0; c < 12; ++c) orow[lane + 64 * c] = acc[c] * inv;
}

extern "C" void kernel_launch(void* const* d_in, const int* in_sizes, int n_in,
                              void* d_out, int out_size, void* d_ws, size_t ws_size,
                              hipStream_t stream) {
  const float* hi1 = (const float*)d_in[0];
  const float* hi2 = (const float*)d_in[1];
  const float* wg  = (const float*)d_in[2];
  float* out = (float*)d_out;

  char* ws = (char*)d_ws;
  const size_t plane_elems = (size_t)BB * LL1 * HH;   // 25.17M
  const size_t plane_b = plane_elems * 2;             // 50.33MB (fp16)
  const size_t wt_b = (size_t)HH * HH * 2;            // 1.18MB
  const size_t s_per_b = (size_t)LL1 * LL2 * 4;       // 16.78MB (fp32 S)

  _Float16* H2f = (_Float16*)ws;
  _Float16* Gf  = (_Float16*)(ws + plane_b);
  _Float16* Wtf = (_Float16*)(ws + 2 * plane_b);
  char* X = ws + 2 * plane_b + wt_b;                  // aliased: H1f then Sbuf
  _Float16* H1f = (_Float16*)X;
  float* Sbuf   = (float*)X;

  const size_t fixed = 2 * plane_b + wt_b;
  int CB = 1;
  const int cand[5] = {16, 8, 4, 2, 1};
  for (int i = 0; i < 5; ++i) {
    size_t xneed = (size_t)cand[i] * s_per_b;
    if (xneed < plane_b) xneed = plane_b;             // X also holds H1 plane
    if (fixed + xneed + 1024 <= ws_size) { CB = cand[i]; break; }
  }

  k_split16<<<4096, 256, 0, stream>>>(hi1, H1f, (int)(plane_elems / 4));
  k_split16<<<4096, 256, 0, stream>>>(hi2, H2f, (int)(plane_elems / 4));
  k_split_wt16<<<dim3(HH / 32, HH / 32), 256, 0, stream>>>(wg, Wtf);

  k_gemm_f16<<<dim3(HH / 128, (BB * LL1) / 128), 256, 0, stream>>>(H1f, Wtf, Gf);

  for (int b0 = 0; b0 < BB; b0 += CB) {
    k_scores_f16<<<dim3(LL2 / 128, LL1 / 128, CB), 256, 0, stream>>>(Gf, H2f, Sbuf, b0);
    k_select<<<dim3(LL1 / 4, CB), 256, 0, stream>>>(Sbuf, hi2, out, b0);
  }
}